// Round 2
// baseline (1294.916 us; speedup 1.0000x reference)
//
#include <hip/hip_runtime.h>
#include <cstdint>
#include <cstddef>

typedef __bf16 bf16;
typedef __bf16 bf16x2 __attribute__((ext_vector_type(2)));
typedef __bf16 bf16x8 __attribute__((ext_vector_type(8)));
typedef float  f32x4  __attribute__((ext_vector_type(4)));

#define DEV __device__ __forceinline__

constexpr int Bc = 2, Sc = 2048, Dc = 2048, Hc = 16, KVc = 4, HDc = 128, FFNc = 5632;
constexpr int Rc = Bc * Sc;  // 4096 rows

DEV void async16(const bf16* g, bf16* l) {
  __builtin_amdgcn_global_load_lds((const __attribute__((address_space(1))) void*)g,
                                   (__attribute__((address_space(3))) void*)l, 16, 0, 0);
}

// ---------------- weight transpose + fp32->bf16 cast: out[n][k] = in[k][n] ----
__global__ void transpose_cast(const float* __restrict__ in, bf16* __restrict__ out,
                               int K, int N, int rowoff, int ldout) {
  __shared__ float tile[32][33];
  int k0 = blockIdx.y * 32, n0 = blockIdx.x * 32;
  int tx = threadIdx.x, ty = threadIdx.y;
  for (int r = ty; r < 32; r += 8)
    tile[r][tx] = in[(size_t)(k0 + r) * N + n0 + tx];
  __syncthreads();
  for (int r = ty; r < 32; r += 8)
    out[(size_t)(rowoff + n0 + r) * ldout + k0 + tx] = (bf16)tile[tx][r];
}

// ---------------- row RMSNorm (D=2048) + cast to bf16 ------------------------
__global__ void rmsnorm_cast(const float* __restrict__ x, const float* __restrict__ w,
                             bf16* __restrict__ out) {
  __shared__ float red[4];
  int row = blockIdx.x, tid = threadIdx.x;
  const float* xr = x + (size_t)row * Dc;
  float ss = 0.f;
#pragma unroll
  for (int i = 0; i < Dc / 256; ++i) { float v = xr[tid + i * 256]; ss += v * v; }
  for (int off = 32; off; off >>= 1) ss += __shfl_xor(ss, off);
  if ((tid & 63) == 0) red[tid >> 6] = ss;
  __syncthreads();
  float rstd = rsqrtf((red[0] + red[1] + red[2] + red[3]) * (1.f / Dc) + 1e-6f);
  bf16* orow = out + (size_t)row * Dc;
#pragma unroll
  for (int i = 0; i < Dc / 256; ++i) {
    int j = tid + i * 256;
    orow[j] = (bf16)(xr[j] * rstd * w[j]);
  }
}

// ---------------- m97-style GEMM: C[M,N] = A[M,K] * Bt[N,K]^T ----------------
// MODE 1: velocity update: v=clip(beta*velin+c); velout=v; Cf = xin + v
// MODE 2: store bf16 C at ldc
// MODE 3: Cf = xin + c (in-place residual ok)
template <int MODE>
__global__ __launch_bounds__(256) void gemm_bt(
    const bf16* __restrict__ A, int lda, const bf16* __restrict__ Bt,
    float* __restrict__ Cf, bf16* __restrict__ Cb,
    const float* __restrict__ xin, const float* __restrict__ velin,
    const float* __restrict__ lbp, float* __restrict__ velout,
    int M, int N, int K, int ldc) {
  __shared__ bf16 As[128 * 32];
  __shared__ bf16 Bs[128 * 32];
  const int tid = threadIdx.x, lane = tid & 63, wvid = tid >> 6;
  const int quad = lane >> 4, l15 = lane & 15;
  const int m0 = blockIdx.y * 128, n0 = blockIdx.x * 128;
  const int wr = (wvid >> 1) * 64, wc = (wvid & 1) * 64;
  const int rsub = lane >> 2, chk = lane & 3;

  f32x4 acc[4][4];
  const f32x4 zf = {0.f, 0.f, 0.f, 0.f};
#pragma unroll
  for (int i = 0; i < 4; ++i)
#pragma unroll
    for (int j = 0; j < 4; ++j) acc[i][j] = zf;

  const bf16* Ag = A + (size_t)(m0 + wvid * 32 + rsub) * lda + chk * 8;
  const bf16* Bg = Bt + (size_t)(n0 + wvid * 32 + rsub) * K + chk * 8;
  bf16* Al = As + (wvid * 32) * 32;
  bf16* Bl = Bs + (wvid * 32) * 32;

  for (int k0 = 0; k0 < K; k0 += 32) {
    async16(Ag + k0, Al);
    async16(Ag + (size_t)16 * lda + k0, Al + 16 * 32);
    async16(Bg + k0, Bl);
    async16(Bg + (size_t)16 * K + k0, Bl + 16 * 32);
    __syncthreads();
    bf16x8 af[4], bfr[4];
#pragma unroll
    for (int i = 0; i < 4; ++i) af[i] = *(const bf16x8*)(As + (wr + i * 16 + l15) * 32 + quad * 8);
#pragma unroll
    for (int j = 0; j < 4; ++j) bfr[j] = *(const bf16x8*)(Bs + (wc + j * 16 + l15) * 32 + quad * 8);
#pragma unroll
    for (int i = 0; i < 4; ++i)
#pragma unroll
      for (int j = 0; j < 4; ++j)
        acc[i][j] = __builtin_amdgcn_mfma_f32_16x16x32_bf16(af[i], bfr[j], acc[i][j], 0, 0, 0);
    __syncthreads();
  }

  float beta = 0.f;
  if (MODE == 1) beta = 1.f / (1.f + __expf(-lbp[0]));
#pragma unroll
  for (int i = 0; i < 4; ++i) {
#pragma unroll
    for (int j = 0; j < 4; ++j) {
#pragma unroll
      for (int r = 0; r < 4; ++r) {
        int row = m0 + wr + i * 16 + quad * 4 + r;
        int col = n0 + wc + j * 16 + l15;
        size_t idx = (size_t)row * ldc + col;
        float c = acc[i][j][r];
        if (MODE == 1) {
          float v = beta * velin[idx] + c;
          v = fminf(8.f, fmaxf(-8.f, v));
          velout[idx] = v;
          Cf[idx] = xin[idx] + v;
        } else if (MODE == 2) {
          Cb[idx] = (bf16)c;
        } else {
          Cf[idx] = xin[idx] + c;
        }
      }
    }
  }
}

// ---------------- per-head RMSNorm + RoPE, split to q/k/v head-major bf16 ----
__global__ __launch_bounds__(256) void qk_norm_rope(
    const bf16* __restrict__ qkv, const float* __restrict__ qw, const float* __restrict__ kw,
    const float* __restrict__ freqs, bf16* __restrict__ qh, bf16* __restrict__ kh,
    bf16* __restrict__ vh) {
  int row = blockIdx.x;  // b*S + s
  int b = row >> 11, s = row & 2047;
  int tid = threadIdx.x, wvid = tid >> 6, lane = tid & 63;
  float cs = freqs[(size_t)(s * 64 + lane) * 2 + 0];
  float sn = freqs[(size_t)(s * 64 + lane) * 2 + 1];
  for (int slot = wvid; slot < 24; slot += 4) {
    const bf16* base = qkv + (size_t)row * 3072 + slot * 128;
    float t0 = (float)base[2 * lane], t1 = (float)base[2 * lane + 1];
    if (slot < 20) {
      float ss = t0 * t0 + t1 * t1;
      for (int off = 32; off; off >>= 1) ss += __shfl_xor(ss, off);
      float rstd = rsqrtf(ss * (1.f / 128.f) + 1e-6f);
      const float* w = (slot < 16) ? qw : kw;
      float n0 = t0 * rstd * w[2 * lane], n1 = t1 * rstd * w[2 * lane + 1];
      bf16x2 o;
      o[0] = (bf16)(n0 * cs - n1 * sn);
      o[1] = (bf16)(n0 * sn + n1 * cs);
      if (slot < 16)
        *(bf16x2*)(qh + ((size_t)(b * Hc + slot) * Sc + s) * HDc + 2 * lane) = o;
      else
        *(bf16x2*)(kh + ((size_t)(b * KVc + (slot - 16)) * Sc + s) * HDc + 2 * lane) = o;
    } else {
      bf16x2 o;
      o[0] = (bf16)t0;
      o[1] = (bf16)t1;
      *(bf16x2*)(vh + ((size_t)(b * KVc + (slot - 20)) * Sc + s) * HDc + 2 * lane) = o;
    }
  }
}

// ---------------- strict-causal GQA flash attention --------------------------
// grid (S/64, H, B); block 256 = 4 waves; wave owns 16 q-rows; 32-key K-tiles.
__global__ __launch_bounds__(256) void flash_attn(
    const bf16* __restrict__ qh, const bf16* __restrict__ kh, const bf16* __restrict__ vh,
    bf16* __restrict__ attn) {
  __shared__ bf16 Ks[32 * 136];
  __shared__ bf16 Vs[128 * 40];
  __shared__ bf16 Ps[4 * 16 * 40];
  const int tid = threadIdx.x, lane = tid & 63, wvid = tid >> 6;
  const int quad = lane >> 4, l15 = lane & 15;
  const int qt = gridDim.x - 1 - blockIdx.x;  // long blocks first
  const int h = blockIdx.y, b = blockIdx.z, g = h >> 2;
  const int q0 = qt * 64 + wvid * 16;
  const bf16* qbase = qh + (size_t)(b * Hc + h) * Sc * HDc;
  const bf16* kbase = kh + (size_t)(b * KVc + g) * Sc * HDc;
  const bf16* vbase = vh + (size_t)(b * KVc + g) * Sc * HDc;

  bf16x8 qf[4];
#pragma unroll
  for (int f = 0; f < 4; ++f)
    qf[f] = *(const bf16x8*)(qbase + (size_t)(q0 + l15) * HDc + f * 32 + quad * 8);

  const f32x4 zf = {0.f, 0.f, 0.f, 0.f};
  f32x4 Oa[8];
#pragma unroll
  for (int i = 0; i < 8; ++i) Oa[i] = zf;
  float m_i[4], l_i[4];
#pragma unroll
  for (int r = 0; r < 4; ++r) { m_i[r] = -3e38f; l_i[r] = 0.f; }

  const int ntiles = 2 * qt + 2;
  const float scale = 0.08838834764831845f;  // 1/sqrt(128)
  bf16* pw = Ps + wvid * 16 * 40;

  for (int kt = 0; kt < ntiles; ++kt) {
    const int k0 = kt * 32;
    __syncthreads();
    {
      int ch = tid & 15;
#pragma unroll
      for (int it = 0; it < 2; ++it) {
        int kk = (tid >> 4) + it * 16;
        bf16x8 kvv = *(const bf16x8*)(kbase + (size_t)(k0 + kk) * HDc + ch * 8);
        *(bf16x8*)(Ks + kk * 136 + ch * 8) = kvv;
        bf16x8 vvv = *(const bf16x8*)(vbase + (size_t)(k0 + kk) * HDc + ch * 8);
#pragma unroll
        for (int e = 0; e < 8; ++e) Vs[(ch * 8 + e) * 40 + kk] = vvv[e];
      }
    }
    __syncthreads();

    f32x4 sc0 = zf, sc1 = zf;
#pragma unroll
    for (int f = 0; f < 4; ++f) {
      bf16x8 kf = *(const bf16x8*)(Ks + l15 * 136 + f * 32 + quad * 8);
      sc0 = __builtin_amdgcn_mfma_f32_16x16x32_bf16(qf[f], kf, sc0, 0, 0, 0);
    }
#pragma unroll
    for (int f = 0; f < 4; ++f) {
      bf16x8 kf = *(const bf16x8*)(Ks + (16 + l15) * 136 + f * 32 + quad * 8);
      sc1 = __builtin_amdgcn_mfma_f32_16x16x32_bf16(qf[f], kf, sc1, 0, 0, 0);
    }

    float mx[4], al[4], rs[4];
#pragma unroll
    for (int r = 0; r < 4; ++r) {
      int qg = q0 + quad * 4 + r;
      float s0 = (k0 + l15 < qg) ? sc0[r] * scale : -3e38f;  // strict causal k<q
      float s1 = (k0 + 16 + l15 < qg) ? sc1[r] * scale : -3e38f;
      sc0[r] = s0; sc1[r] = s1;
      mx[r] = fmaxf(s0, s1);
    }
#pragma unroll
    for (int off = 8; off; off >>= 1)
#pragma unroll
      for (int r = 0; r < 4; ++r) mx[r] = fmaxf(mx[r], __shfl_xor(mx[r], off));
#pragma unroll
    for (int r = 0; r < 4; ++r) {
      float mn = fmaxf(m_i[r], mx[r]);
      al[r] = __expf(m_i[r] - mn);
      m_i[r] = mn;
      float p0 = (sc0[r] > -1e37f) ? __expf(sc0[r] - mn) : 0.f;
      float p1 = (sc1[r] > -1e37f) ? __expf(sc1[r] - mn) : 0.f;
      sc0[r] = p0; sc1[r] = p1;
      rs[r] = p0 + p1;
    }
#pragma unroll
    for (int off = 8; off; off >>= 1)
#pragma unroll
      for (int r = 0; r < 4; ++r) rs[r] += __shfl_xor(rs[r], off);
#pragma unroll
    for (int r = 0; r < 4; ++r) l_i[r] = l_i[r] * al[r] + rs[r];
#pragma unroll
    for (int i = 0; i < 8; ++i)
#pragma unroll
      for (int r = 0; r < 4; ++r) Oa[i][r] *= al[r];

#pragma unroll
    for (int r = 0; r < 4; ++r) {
      pw[(quad * 4 + r) * 40 + l15] = (bf16)sc0[r];
      pw[(quad * 4 + r) * 40 + 16 + l15] = (bf16)sc1[r];
    }
    __syncthreads();
    bf16x8 pf = *(const bf16x8*)(pw + l15 * 40 + quad * 8);
#pragma unroll
    for (int i = 0; i < 8; ++i) {
      bf16x8 vf = *(const bf16x8*)(Vs + (i * 16 + l15) * 40 + quad * 8);
      Oa[i] = __builtin_amdgcn_mfma_f32_16x16x32_bf16(pf, vf, Oa[i], 0, 0, 0);
    }
  }

#pragma unroll
  for (int r = 0; r < 4; ++r) {
    float inv = (l_i[r] > 0.f) ? 1.f / l_i[r] : 0.f;  // q=0 row fully masked -> 0
    int qg = q0 + quad * 4 + r;
    bf16* orow = attn + (size_t)(b * Sc + qg) * Dc + h * HDc;
#pragma unroll
    for (int i = 0; i < 8; ++i) orow[i * 16 + l15] = (bf16)(Oa[i][r] * inv);
  }
}

// ---------------- SwiGLU in-place: g[:, :5632] = silu(g1)*g3 -----------------
__global__ __launch_bounds__(256) void silu_mul_ip(bf16* __restrict__ g) {
  int row = blockIdx.y * 4 + (threadIdx.x >> 6);
  int j0 = (blockIdx.x * 64 + (threadIdx.x & 63)) * 8;
  bf16* p = g + (size_t)row * (2 * FFNc) + j0;
  const bf16x8 a = *(const bf16x8*)p;
  const bf16x8 bb = *(const bf16x8*)(p + FFNc);
  bf16x8 o;
#pragma unroll
  for (int e = 0; e < 8; ++e) {
    float xa = (float)a[e], xb = (float)bb[e];
    float s = xa / (1.f + __expf(-xa));
    o[e] = (bf16)(s * xb);
  }
  *(bf16x8*)p = o;
}

// ---------------- launch ------------------------------------------------------
extern "C" void kernel_launch(void* const* d_in, const int* in_sizes, int n_in,
                              void* d_out, int out_size, void* d_ws, size_t ws_size,
                              hipStream_t stream) {
  (void)in_sizes; (void)n_in; (void)out_size; (void)ws_size;
  const float* x    = (const float*)d_in[0];
  const float* vel  = (const float*)d_in[1];
  const float* frq  = (const float*)d_in[2];
  const float* prew = (const float*)d_in[3];
  const float* wq   = (const float*)d_in[4];
  const float* wk   = (const float*)d_in[5];
  const float* wvw  = (const float*)d_in[6];
  const float* wo   = (const float*)d_in[7];
  const float* qnw  = (const float*)d_in[8];
  const float* knw  = (const float*)d_in[9];
  const float* lb   = (const float*)d_in[10];
  const float* ffnw = (const float*)d_in[11];
  const float* w1   = (const float*)d_in[12];
  const float* w3   = (const float*)d_in[13];
  const float* w2   = (const float*)d_in[14];

  float* out0 = (float*)d_out;                  // final x (also residual scratch)
  float* out1 = out0 + (size_t)Rc * Dc;         // velocity

  // ---- workspace arena: 126 MiB total (fits a 128 MiB d_ws) ----
  char* ws = (char*)d_ws;
  bf16* W  = (bf16*)ws;                                   // 23.07 MB weight region (serial reuse)
  bf16* R1 = (bf16*)(ws + (size_t)23068672);              // 16.78 MB: hbuf -> attn -> normed
  bf16* G  = (bf16*)(ws + (size_t)23068672 + 16777216);   // 92.27 MB: qkv/heads -> gbuf
  bf16* hbuf   = R1;
  bf16* attn   = R1;
  bf16* normed = R1;
  bf16* qkvb   = G;                                       // 4096 x 3072 bf16
  bf16* qhb    = G + (size_t)4096 * 3072;                 // 2*16*2048*128
  bf16* khb    = qhb + (size_t)2 * 16 * 2048 * 128;       // 2*4*2048*128
  bf16* vhb    = khb + (size_t)2 * 4 * 2048 * 128;
  bf16* gbuf   = G;                                       // 4096 x 11264 (born after heads die)

  dim3 tb(32, 8);

  // QKV projection
  transpose_cast<<<dim3(64, 64), tb, 0, stream>>>(wq, W, 2048, 2048, 0, 2048);
  transpose_cast<<<dim3(16, 64), tb, 0, stream>>>(wk, W, 2048, 512, 2048, 2048);
  transpose_cast<<<dim3(16, 64), tb, 0, stream>>>(wvw, W, 2048, 512, 2560, 2048);
  rmsnorm_cast<<<Rc, 256, 0, stream>>>(x, prew, hbuf);
  gemm_bt<2><<<dim3(24, 32), 256, 0, stream>>>(hbuf, 2048, W, nullptr, qkvb, nullptr, nullptr,
                                               nullptr, nullptr, 4096, 3072, 2048, 3072);
  qk_norm_rope<<<Rc, 256, 0, stream>>>(qkvb, qnw, knw, frq, qhb, khb, vhb);

  // attention + Wo + velocity/residual (writes out0, out1)
  flash_attn<<<dim3(Sc / 64, Hc, Bc), 256, 0, stream>>>(qhb, khb, vhb, attn);
  transpose_cast<<<dim3(64, 64), tb, 0, stream>>>(wo, W, 2048, 2048, 0, 2048);
  gemm_bt<1><<<dim3(16, 32), 256, 0, stream>>>(attn, 2048, W, out0, nullptr, x, vel, lb, out1,
                                               4096, 2048, 2048, 2048);

  // FFN
  rmsnorm_cast<<<Rc, 256, 0, stream>>>(out0, ffnw, normed);
  transpose_cast<<<dim3(176, 64), tb, 0, stream>>>(w1, W, 2048, 5632, 0, 2048);
  gemm_bt<2><<<dim3(44, 32), 256, 0, stream>>>(normed, 2048, W, nullptr, gbuf, nullptr, nullptr,
                                               nullptr, nullptr, 4096, 5632, 2048, 11264);
  transpose_cast<<<dim3(176, 64), tb, 0, stream>>>(w3, W, 2048, 5632, 0, 2048);
  gemm_bt<2><<<dim3(44, 32), 256, 0, stream>>>(normed, 2048, W, nullptr, gbuf + FFNc, nullptr,
                                               nullptr, nullptr, nullptr, 4096, 5632, 2048, 11264);
  silu_mul_ip<<<dim3(11, 1024), 256, 0, stream>>>(gbuf);
  transpose_cast<<<dim3(64, 176), tb, 0, stream>>>(w2, W, 5632, 2048, 0, 5632);
  gemm_bt<3><<<dim3(16, 32), 256, 0, stream>>>(gbuf, 11264, W, out0, nullptr, out0, nullptr,
                                               nullptr, nullptr, 4096, 2048, 5632, 2048);
}

// Round 3
// 1015.535 us; speedup vs baseline: 1.2751x; 1.2751x over previous
//
#include <hip/hip_runtime.h>
#include <cstdint>
#include <cstddef>

typedef __bf16 bf16;
typedef __bf16 bf16x2 __attribute__((ext_vector_type(2)));
typedef __bf16 bf16x8 __attribute__((ext_vector_type(8)));
typedef float  f32x4  __attribute__((ext_vector_type(4)));

#define DEV __device__ __forceinline__

constexpr int Bc = 2, Sc = 2048, Dc = 2048, Hc = 16, KVc = 4, HDc = 128, FFNc = 5632;
constexpr int Rc = Bc * Sc;  // 4096 rows

DEV void async16(const bf16* g, bf16* l) {
  __builtin_amdgcn_global_load_lds((const __attribute__((address_space(1))) void*)g,
                                   (__attribute__((address_space(3))) void*)l, 16, 0, 0);
}

// ---------------- weight transpose + fp32->bf16 cast: out[n][k] = in[k][n] ----
__global__ void transpose_cast(const float* __restrict__ in, bf16* __restrict__ out,
                               int K, int N, int rowoff, int ldout) {
  __shared__ float tile[32][33];
  int k0 = blockIdx.y * 32, n0 = blockIdx.x * 32;
  int tx = threadIdx.x, ty = threadIdx.y;
  for (int r = ty; r < 32; r += 8)
    tile[r][tx] = in[(size_t)(k0 + r) * N + n0 + tx];
  __syncthreads();
  for (int r = ty; r < 32; r += 8)
    out[(size_t)(rowoff + n0 + r) * ldout + k0 + tx] = (bf16)tile[tx][r];
}

// ---------------- V transpose: vht[b][g][d][s] = qkvb[b*S+s][2560+g*128+d] ---
__global__ void transpose_v(const bf16* __restrict__ qkvb, bf16* __restrict__ vht) {
  __shared__ bf16 tile[32][33];
  int s0 = blockIdx.x * 32, d0 = blockIdx.y * 32, bg = blockIdx.z;  // bg = b*4+g
  int tx = threadIdx.x, ty = threadIdx.y;
  int b = bg >> 2, g = bg & 3;
  const bf16* src = qkvb + (size_t)(b * Sc) * 3072 + 2560 + g * 128;
  for (int r = ty; r < 32; r += 8)
    tile[r][tx] = src[(size_t)(s0 + r) * 3072 + d0 + tx];
  __syncthreads();
  bf16* dst = vht + ((size_t)bg * HDc) * Sc;
  for (int r = ty; r < 32; r += 8)
    dst[(size_t)(d0 + r) * Sc + s0 + tx] = tile[tx][r];
}

// ---------------- row RMSNorm (D=2048) + cast to bf16 ------------------------
__global__ void rmsnorm_cast(const float* __restrict__ x, const float* __restrict__ w,
                             bf16* __restrict__ out) {
  __shared__ float red[4];
  int row = blockIdx.x, tid = threadIdx.x;
  const float* xr = x + (size_t)row * Dc;
  float ss = 0.f;
#pragma unroll
  for (int i = 0; i < Dc / 256; ++i) { float v = xr[tid + i * 256]; ss += v * v; }
  for (int off = 32; off; off >>= 1) ss += __shfl_xor(ss, off);
  if ((tid & 63) == 0) red[tid >> 6] = ss;
  __syncthreads();
  float rstd = rsqrtf((red[0] + red[1] + red[2] + red[3]) * (1.f / Dc) + 1e-6f);
  bf16* orow = out + (size_t)row * Dc;
#pragma unroll
  for (int i = 0; i < Dc / 256; ++i) {
    int j = tid + i * 256;
    orow[j] = (bf16)(xr[j] * rstd * w[j]);
  }
}

// ---------------- m97-style GEMM: C[M,N] = A[M,K] * Bt[N,K]^T ----------------
// MODE 1: velocity update: v=clip(beta*velin+c); velout=v; Cf = xin + v
// MODE 2: store bf16 C at ldc
// MODE 3: Cf = xin + c (in-place residual ok)
template <int MODE>
__global__ __launch_bounds__(256) void gemm_bt(
    const bf16* __restrict__ A, int lda, const bf16* __restrict__ Bt,
    float* __restrict__ Cf, bf16* __restrict__ Cb,
    const float* __restrict__ xin, const float* __restrict__ velin,
    const float* __restrict__ lbp, float* __restrict__ velout,
    int M, int N, int K, int ldc) {
  __shared__ bf16 As[128 * 32];
  __shared__ bf16 Bs[128 * 32];
  const int tid = threadIdx.x, lane = tid & 63, wvid = tid >> 6;
  const int quad = lane >> 4, l15 = lane & 15;
  const int m0 = blockIdx.y * 128, n0 = blockIdx.x * 128;
  const int wr = (wvid >> 1) * 64, wc = (wvid & 1) * 64;
  const int rsub = lane >> 2, chk = lane & 3;

  f32x4 acc[4][4];
  const f32x4 zf = {0.f, 0.f, 0.f, 0.f};
#pragma unroll
  for (int i = 0; i < 4; ++i)
#pragma unroll
    for (int j = 0; j < 4; ++j) acc[i][j] = zf;

  const bf16* Ag = A + (size_t)(m0 + wvid * 32 + rsub) * lda + chk * 8;
  const bf16* Bg = Bt + (size_t)(n0 + wvid * 32 + rsub) * K + chk * 8;
  bf16* Al = As + (wvid * 32) * 32;
  bf16* Bl = Bs + (wvid * 32) * 32;

  for (int k0 = 0; k0 < K; k0 += 32) {
    async16(Ag + k0, Al);
    async16(Ag + (size_t)16 * lda + k0, Al + 16 * 32);
    async16(Bg + k0, Bl);
    async16(Bg + (size_t)16 * K + k0, Bl + 16 * 32);
    __syncthreads();
    bf16x8 af[4], bfr[4];
#pragma unroll
    for (int i = 0; i < 4; ++i) af[i] = *(const bf16x8*)(As + (wr + i * 16 + l15) * 32 + quad * 8);
#pragma unroll
    for (int j = 0; j < 4; ++j) bfr[j] = *(const bf16x8*)(Bs + (wc + j * 16 + l15) * 32 + quad * 8);
#pragma unroll
    for (int i = 0; i < 4; ++i)
#pragma unroll
      for (int j = 0; j < 4; ++j)
        acc[i][j] = __builtin_amdgcn_mfma_f32_16x16x32_bf16(af[i], bfr[j], acc[i][j], 0, 0, 0);
    __syncthreads();
  }

  float beta = 0.f;
  if (MODE == 1) beta = 1.f / (1.f + __expf(-lbp[0]));
#pragma unroll
  for (int i = 0; i < 4; ++i) {
#pragma unroll
    for (int j = 0; j < 4; ++j) {
#pragma unroll
      for (int r = 0; r < 4; ++r) {
        int row = m0 + wr + i * 16 + quad * 4 + r;
        int col = n0 + wc + j * 16 + l15;
        size_t idx = (size_t)row * ldc + col;
        float c = acc[i][j][r];
        if (MODE == 1) {
          float v = beta * velin[idx] + c;
          v = fminf(8.f, fmaxf(-8.f, v));
          velout[idx] = v;
          Cf[idx] = xin[idx] + v;
        } else if (MODE == 2) {
          Cb[idx] = (bf16)c;
        } else {
          Cf[idx] = xin[idx] + c;
        }
      }
    }
  }
}

// ---------------- per-head RMSNorm + RoPE for q,k (v handled separately) -----
// q outputs pre-scaled by 1/sqrt(HD).
__global__ __launch_bounds__(256) void qk_norm_rope(
    const bf16* __restrict__ qkv, const float* __restrict__ qw, const float* __restrict__ kw,
    const float* __restrict__ freqs, bf16* __restrict__ qh, bf16* __restrict__ kh) {
  int row = blockIdx.x;  // b*S + s
  int b = row >> 11, s = row & 2047;
  int tid = threadIdx.x, wvid = tid >> 6, lane = tid & 63;
  float cs = freqs[(size_t)(s * 64 + lane) * 2 + 0];
  float sn = freqs[(size_t)(s * 64 + lane) * 2 + 1];
  for (int slot = wvid; slot < 20; slot += 4) {
    const bf16* base = qkv + (size_t)row * 3072 + slot * 128;
    float t0 = (float)base[2 * lane], t1 = (float)base[2 * lane + 1];
    float ss = t0 * t0 + t1 * t1;
    for (int off = 32; off; off >>= 1) ss += __shfl_xor(ss, off);
    float rstd = rsqrtf(ss * (1.f / 128.f) + 1e-6f);
    const float* w = (slot < 16) ? qw : kw;
    float sc = (slot < 16) ? 0.08838834764831845f : 1.f;  // fold 1/sqrt(128) into q
    float n0 = t0 * rstd * w[2 * lane], n1 = t1 * rstd * w[2 * lane + 1];
    bf16x2 o;
    o[0] = (bf16)((n0 * cs - n1 * sn) * sc);
    o[1] = (bf16)((n0 * sn + n1 * cs) * sc);
    if (slot < 16)
      *(bf16x2*)(qh + ((size_t)(b * Hc + slot) * Sc + s) * HDc + 2 * lane) = o;
    else
      *(bf16x2*)(kh + ((size_t)(b * KVc + (slot - 16)) * Sc + s) * HDc + 2 * lane) = o;
  }
}

// ---------------- strict-causal GQA flash attention --------------------------
// grid (16 pairs, H, B); block 256 = 4 waves; wave owns 16 q-rows.
// Block processes q-tiles p and 31-p (counter-diagonal pairing -> uniform 68
// k-tile iterations per block; 512 blocks = 2/CU, perfectly balanced).
__global__ __launch_bounds__(256) void flash_attn(
    const bf16* __restrict__ qh, const bf16* __restrict__ kh, const bf16* __restrict__ vht,
    bf16* __restrict__ attn) {
  __shared__ bf16 Ks[32 * 136];     // [k][d] pitch 136
  __shared__ bf16 Vs[128 * 40];     // [d][k] pitch 40 (staged from pre-transposed vht)
  __shared__ bf16 Ps[4 * 16 * 40];  // per-wave P transpose scratch
  const int tid = threadIdx.x, lane = tid & 63, wvid = tid >> 6;
  const int quad = lane >> 4, l15 = lane & 15;
  const int pairp = blockIdx.x;
  const int h = blockIdx.y, b = blockIdx.z, g = h >> 2;
  const bf16* qbase = qh + (size_t)(b * Hc + h) * Sc * HDc;
  const bf16* kbase = kh + (size_t)(b * KVc + g) * Sc * HDc;
  const bf16* vbase = vht + (size_t)(b * KVc + g) * HDc * Sc;  // [d][s]
  const f32x4 zf = {0.f, 0.f, 0.f, 0.f};
  bf16* pw = Ps + wvid * 16 * 40;

  for (int pass = 0; pass < 2; ++pass) {
    const int qt = pass ? 31 - pairp : pairp;
    const int q0 = qt * 64 + wvid * 16;

    bf16x8 qf[4];
#pragma unroll
    for (int f = 0; f < 4; ++f)
      qf[f] = *(const bf16x8*)(qbase + (size_t)(q0 + l15) * HDc + f * 32 + quad * 8);

    f32x4 Oa[8];
#pragma unroll
    for (int i = 0; i < 8; ++i) Oa[i] = zf;
    float m_i[4], l_i[4];
#pragma unroll
    for (int r = 0; r < 4; ++r) { m_i[r] = -3e38f; l_i[r] = 0.f; }

    const int ntiles = 2 * qt + 2;

    for (int kt = 0; kt < ntiles; ++kt) {
      const int k0 = kt * 32;
      __syncthreads();  // protect Ks/Vs/Ps from previous iteration's readers
      {
        int ch = tid & 15, kk = tid >> 4;       // K: [32k][128d]
#pragma unroll
        for (int it = 0; it < 2; ++it) {
          int kk2 = kk + it * 16;
          *(bf16x8*)(Ks + kk2 * 136 + ch * 8) =
              *(const bf16x8*)(kbase + (size_t)(k0 + kk2) * HDc + ch * 8);
        }
        int dd = tid >> 2, ck = tid & 3;        // V^T: [128d][32k]
#pragma unroll
        for (int it = 0; it < 2; ++it) {
          int d2 = dd + it * 64;
          *(bf16x8*)(Vs + d2 * 40 + ck * 8) =
              *(const bf16x8*)(vbase + (size_t)d2 * Sc + k0 + ck * 8);
        }
      }
      __syncthreads();

      f32x4 sc0 = zf, sc1 = zf;
#pragma unroll
      for (int f = 0; f < 4; ++f) {
        bf16x8 kf = *(const bf16x8*)(Ks + l15 * 136 + f * 32 + quad * 8);
        sc0 = __builtin_amdgcn_mfma_f32_16x16x32_bf16(qf[f], kf, sc0, 0, 0, 0);
      }
#pragma unroll
      for (int f = 0; f < 4; ++f) {
        bf16x8 kf = *(const bf16x8*)(Ks + (16 + l15) * 136 + f * 32 + quad * 8);
        sc1 = __builtin_amdgcn_mfma_f32_16x16x32_bf16(qf[f], kf, sc1, 0, 0, 0);
      }

      float mx[4], al[4], rs[4];
#pragma unroll
      for (int r = 0; r < 4; ++r) {
        int qg = q0 + quad * 4 + r;
        float s0 = (k0 + l15 < qg) ? sc0[r] : -3e38f;       // strict causal k<q
        float s1 = (k0 + 16 + l15 < qg) ? sc1[r] : -3e38f;  // (q pre-scaled)
        sc0[r] = s0; sc1[r] = s1;
        mx[r] = fmaxf(s0, s1);
      }
#pragma unroll
      for (int off = 8; off; off >>= 1)
#pragma unroll
        for (int r = 0; r < 4; ++r) mx[r] = fmaxf(mx[r], __shfl_xor(mx[r], off));
#pragma unroll
      for (int r = 0; r < 4; ++r) {
        float mn = fmaxf(m_i[r], mx[r]);
        al[r] = __expf(m_i[r] - mn);
        m_i[r] = mn;
        float p0 = (sc0[r] > -1e37f) ? __expf(sc0[r] - mn) : 0.f;
        float p1 = (sc1[r] > -1e37f) ? __expf(sc1[r] - mn) : 0.f;
        sc0[r] = p0; sc1[r] = p1;
        rs[r] = p0 + p1;
      }
#pragma unroll
      for (int off = 8; off; off >>= 1)
#pragma unroll
        for (int r = 0; r < 4; ++r) rs[r] += __shfl_xor(rs[r], off);
#pragma unroll
      for (int r = 0; r < 4; ++r) l_i[r] = l_i[r] * al[r] + rs[r];
#pragma unroll
      for (int i = 0; i < 8; ++i)
#pragma unroll
        for (int r = 0; r < 4; ++r) Oa[i][r] *= al[r];

#pragma unroll
      for (int r = 0; r < 4; ++r) {
        pw[(quad * 4 + r) * 40 + l15] = (bf16)sc0[r];
        pw[(quad * 4 + r) * 40 + 16 + l15] = (bf16)sc1[r];
      }
      __syncthreads();
      bf16x8 pf = *(const bf16x8*)(pw + l15 * 40 + quad * 8);
#pragma unroll
      for (int i = 0; i < 8; ++i) {
        bf16x8 vf = *(const bf16x8*)(Vs + (i * 16 + l15) * 40 + quad * 8);
        Oa[i] = __builtin_amdgcn_mfma_f32_16x16x32_bf16(pf, vf, Oa[i], 0, 0, 0);
      }
    }

#pragma unroll
    for (int r = 0; r < 4; ++r) {
      float inv = (l_i[r] > 0.f) ? 1.f / l_i[r] : 0.f;  // q=0 row fully masked -> 0
      int qg = q0 + quad * 4 + r;
      bf16* orow = attn + (size_t)(b * Sc + qg) * Dc + h * HDc;
#pragma unroll
      for (int i = 0; i < 8; ++i) orow[i * 16 + l15] = (bf16)(Oa[i][r] * inv);
    }
  }
}

// ---------------- SwiGLU in-place: g[:, :5632] = silu(g1)*g3 -----------------
__global__ __launch_bounds__(256) void silu_mul_ip(bf16* __restrict__ g) {
  int row = blockIdx.y * 4 + (threadIdx.x >> 6);
  int j0 = (blockIdx.x * 64 + (threadIdx.x & 63)) * 8;
  bf16* p = g + (size_t)row * (2 * FFNc) + j0;
  const bf16x8 a = *(const bf16x8*)p;
  const bf16x8 bb = *(const bf16x8*)(p + FFNc);
  bf16x8 o;
#pragma unroll
  for (int e = 0; e < 8; ++e) {
    float xa = (float)a[e], xb = (float)bb[e];
    float s = xa / (1.f + __expf(-xa));
    o[e] = (bf16)(s * xb);
  }
  *(bf16x8*)p = o;
}

// ---------------- launch ------------------------------------------------------
extern "C" void kernel_launch(void* const* d_in, const int* in_sizes, int n_in,
                              void* d_out, int out_size, void* d_ws, size_t ws_size,
                              hipStream_t stream) {
  (void)in_sizes; (void)n_in; (void)out_size; (void)ws_size;
  const float* x    = (const float*)d_in[0];
  const float* vel  = (const float*)d_in[1];
  const float* frq  = (const float*)d_in[2];
  const float* prew = (const float*)d_in[3];
  const float* wq   = (const float*)d_in[4];
  const float* wk   = (const float*)d_in[5];
  const float* wvw  = (const float*)d_in[6];
  const float* wo   = (const float*)d_in[7];
  const float* qnw  = (const float*)d_in[8];
  const float* knw  = (const float*)d_in[9];
  const float* lb   = (const float*)d_in[10];
  const float* ffnw = (const float*)d_in[11];
  const float* w1   = (const float*)d_in[12];
  const float* w3   = (const float*)d_in[13];
  const float* w2   = (const float*)d_in[14];

  float* out0 = (float*)d_out;                  // final x (also residual scratch)
  float* out1 = out0 + (size_t)Rc * Dc;         // velocity

  // ---- workspace arena: 126 MiB total ----
  char* ws = (char*)d_ws;
  bf16* W  = (bf16*)ws;                                   // 23.07 MB weight region (serial reuse)
  bf16* R1 = (bf16*)(ws + (size_t)23068672);              // 16.78 MB: hbuf -> attn -> normed
  bf16* G  = (bf16*)(ws + (size_t)23068672 + 16777216);   // 92.27 MB: qkv/heads -> gbuf
  bf16* hbuf   = R1;
  bf16* attn   = R1;
  bf16* normed = R1;
  bf16* qkvb   = G;                                       // 4096 x 3072 bf16
  bf16* qhb    = G + (size_t)4096 * 3072;                 // 2*16*2048*128
  bf16* khb    = qhb + (size_t)2 * 16 * 2048 * 128;       // 2*4*2048*128
  bf16* vht    = khb + (size_t)2 * 4 * 2048 * 128;        // V^T [b][g][128][2048]
  bf16* gbuf   = G;                                       // 4096 x 11264 (born after heads die)

  dim3 tb(32, 8);

  // QKV projection
  transpose_cast<<<dim3(64, 64), tb, 0, stream>>>(wq, W, 2048, 2048, 0, 2048);
  transpose_cast<<<dim3(16, 64), tb, 0, stream>>>(wk, W, 2048, 512, 2048, 2048);
  transpose_cast<<<dim3(16, 64), tb, 0, stream>>>(wvw, W, 2048, 512, 2560, 2048);
  rmsnorm_cast<<<Rc, 256, 0, stream>>>(x, prew, hbuf);
  gemm_bt<2><<<dim3(24, 32), 256, 0, stream>>>(hbuf, 2048, W, nullptr, qkvb, nullptr, nullptr,
                                               nullptr, nullptr, 4096, 3072, 2048, 3072);
  qk_norm_rope<<<Rc, 256, 0, stream>>>(qkvb, qnw, knw, frq, qhb, khb);
  transpose_v<<<dim3(64, 4, 8), tb, 0, stream>>>(qkvb, vht);

  // attention + Wo + velocity/residual (writes out0, out1)
  flash_attn<<<dim3(16, Hc, Bc), 256, 0, stream>>>(qhb, khb, vht, attn);
  transpose_cast<<<dim3(64, 64), tb, 0, stream>>>(wo, W, 2048, 2048, 0, 2048);
  gemm_bt<1><<<dim3(16, 32), 256, 0, stream>>>(attn, 2048, W, out0, nullptr, x, vel, lb, out1,
                                               4096, 2048, 2048, 2048);

  // FFN
  rmsnorm_cast<<<Rc, 256, 0, stream>>>(out0, ffnw, normed);
  transpose_cast<<<dim3(176, 64), tb, 0, stream>>>(w1, W, 2048, 5632, 0, 2048);
  gemm_bt<2><<<dim3(44, 32), 256, 0, stream>>>(normed, 2048, W, nullptr, gbuf, nullptr, nullptr,
                                               nullptr, nullptr, 4096, 5632, 2048, 11264);
  transpose_cast<<<dim3(176, 64), tb, 0, stream>>>(w3, W, 2048, 5632, 0, 2048);
  gemm_bt<2><<<dim3(44, 32), 256, 0, stream>>>(normed, 2048, W, nullptr, gbuf + FFNc, nullptr,
                                               nullptr, nullptr, nullptr, 4096, 5632, 2048, 11264);
  silu_mul_ip<<<dim3(11, 1024), 256, 0, stream>>>(gbuf);
  transpose_cast<<<dim3(64, 176), tb, 0, stream>>>(w2, W, 5632, 2048, 0, 5632);
  gemm_bt<3><<<dim3(16, 32), 256, 0, stream>>>(gbuf, 11264, W, out0, nullptr, out0, nullptr,
                                               nullptr, nullptr, 4096, 2048, 5632, 2048);
}

// Round 4
// 935.556 us; speedup vs baseline: 1.3841x; 1.0855x over previous
//
#include <hip/hip_runtime.h>
#include <cstdint>
#include <cstddef>

typedef __bf16 bf16;
typedef __bf16 bf16x2 __attribute__((ext_vector_type(2)));
typedef __bf16 bf16x8 __attribute__((ext_vector_type(8)));
typedef float  f32x4  __attribute__((ext_vector_type(4)));

#define DEV __device__ __forceinline__

constexpr int Bc = 2, Sc = 2048, Dc = 2048, Hc = 16, KVc = 4, HDc = 128, FFNc = 5632;
constexpr int Rc = Bc * Sc;  // 4096 rows

DEV void async16(const bf16* g, bf16* l) {
  __builtin_amdgcn_global_load_lds((const __attribute__((address_space(1))) void*)g,
                                   (__attribute__((address_space(3))) void*)l, 16, 0, 0);
}

// ---------------- weight transpose + fp32->bf16 cast: out[n][k] = in[k][n] ----
__global__ void transpose_cast(const float* __restrict__ in, bf16* __restrict__ out,
                               int K, int N, int rowoff, int ldout) {
  __shared__ float tile[32][33];
  int k0 = blockIdx.y * 32, n0 = blockIdx.x * 32;
  int tx = threadIdx.x, ty = threadIdx.y;
  for (int r = ty; r < 32; r += 8)
    tile[r][tx] = in[(size_t)(k0 + r) * N + n0 + tx];
  __syncthreads();
  for (int r = ty; r < 32; r += 8)
    out[(size_t)(rowoff + n0 + r) * ldout + k0 + tx] = (bf16)tile[tx][r];
}

// ---------------- V transpose: vht[b][g][d][s] = qkvb[b*S+s][2560+g*128+d] ---
__global__ void transpose_v(const bf16* __restrict__ qkvb, bf16* __restrict__ vht) {
  __shared__ bf16 tile[32][33];
  int s0 = blockIdx.x * 32, d0 = blockIdx.y * 32, bg = blockIdx.z;  // bg = b*4+g
  int tx = threadIdx.x, ty = threadIdx.y;
  int b = bg >> 2, g = bg & 3;
  const bf16* src = qkvb + (size_t)(b * Sc) * 3072 + 2560 + g * 128;
  for (int r = ty; r < 32; r += 8)
    tile[r][tx] = src[(size_t)(s0 + r) * 3072 + d0 + tx];
  __syncthreads();
  bf16* dst = vht + ((size_t)bg * HDc) * Sc;
  for (int r = ty; r < 32; r += 8)
    dst[(size_t)(d0 + r) * Sc + s0 + tx] = tile[tx][r];
}

// ---------------- row RMSNorm (D=2048) + cast to bf16 ------------------------
__global__ void rmsnorm_cast(const float* __restrict__ x, const float* __restrict__ w,
                             bf16* __restrict__ out) {
  __shared__ float red[4];
  int row = blockIdx.x, tid = threadIdx.x;
  const float* xr = x + (size_t)row * Dc;
  float ss = 0.f;
#pragma unroll
  for (int i = 0; i < Dc / 256; ++i) { float v = xr[tid + i * 256]; ss += v * v; }
  for (int off = 32; off; off >>= 1) ss += __shfl_xor(ss, off);
  if ((tid & 63) == 0) red[tid >> 6] = ss;
  __syncthreads();
  float rstd = rsqrtf((red[0] + red[1] + red[2] + red[3]) * (1.f / Dc) + 1e-6f);
  bf16* orow = out + (size_t)row * Dc;
#pragma unroll
  for (int i = 0; i < Dc / 256; ++i) {
    int j = tid + i * 256;
    orow[j] = (bf16)(xr[j] * rstd * w[j]);
  }
}

// ---------------- m97-style GEMM, BK=64 as dual 32-tiles per barrier round ---
// C[M,N] = A[M,K] * Bt[N,K]^T ; K % 64 == 0
// MODE 1: velocity update: v=clip(beta*velin+c); velout=v; Cf = xin + v
// MODE 2: store bf16 C at ldc
// MODE 3: Cf = xin + c (in-place residual ok)
template <int MODE>
__global__ __launch_bounds__(256) void gemm_bt(
    const bf16* __restrict__ A, int lda, const bf16* __restrict__ Bt,
    float* __restrict__ Cf, bf16* __restrict__ Cb,
    const float* __restrict__ xin, const float* __restrict__ velin,
    const float* __restrict__ lbp, float* __restrict__ velout,
    int M, int N, int K, int ldc) {
  __shared__ bf16 As[2][128 * 32];   // two pitch-32 tiles: keeps async16 contiguity
  __shared__ bf16 Bs[2][128 * 32];   // and the conflict-free 64B-row ds_read pattern
  const int tid = threadIdx.x, lane = tid & 63, wvid = tid >> 6;
  const int quad = lane >> 4, l15 = lane & 15;
  const int m0 = blockIdx.y * 128, n0 = blockIdx.x * 128;
  const int wr = (wvid >> 1) * 64, wc = (wvid & 1) * 64;
  const int rsub = lane >> 2, chk = lane & 3;

  f32x4 acc[4][4];
  const f32x4 zf = {0.f, 0.f, 0.f, 0.f};
#pragma unroll
  for (int i = 0; i < 4; ++i)
#pragma unroll
    for (int j = 0; j < 4; ++j) acc[i][j] = zf;

  const bf16* Ag = A + (size_t)(m0 + wvid * 32 + rsub) * lda + chk * 8;
  const bf16* Bg = Bt + (size_t)(n0 + wvid * 32 + rsub) * K + chk * 8;
  const int lo = (wvid * 32) * 32;

  for (int k0 = 0; k0 < K; k0 += 64) {
#pragma unroll
    for (int hhalf = 0; hhalf < 2; ++hhalf) {
      int kk = k0 + hhalf * 32;
      async16(Ag + kk, As[hhalf] + lo);
      async16(Ag + (size_t)16 * lda + kk, As[hhalf] + lo + 16 * 32);
      async16(Bg + kk, Bs[hhalf] + lo);
      async16(Bg + (size_t)16 * K + kk, Bs[hhalf] + lo + 16 * 32);
    }
    __syncthreads();
#pragma unroll
    for (int hhalf = 0; hhalf < 2; ++hhalf) {
      bf16x8 af[4], bfr[4];
#pragma unroll
      for (int i = 0; i < 4; ++i)
        af[i] = *(const bf16x8*)(As[hhalf] + (wr + i * 16 + l15) * 32 + quad * 8);
#pragma unroll
      for (int j = 0; j < 4; ++j)
        bfr[j] = *(const bf16x8*)(Bs[hhalf] + (wc + j * 16 + l15) * 32 + quad * 8);
#pragma unroll
      for (int i = 0; i < 4; ++i)
#pragma unroll
        for (int j = 0; j < 4; ++j)
          acc[i][j] = __builtin_amdgcn_mfma_f32_16x16x32_bf16(af[i], bfr[j], acc[i][j], 0, 0, 0);
    }
    __syncthreads();
  }

  float beta = 0.f;
  if (MODE == 1) beta = 1.f / (1.f + __expf(-lbp[0]));
#pragma unroll
  for (int i = 0; i < 4; ++i) {
#pragma unroll
    for (int j = 0; j < 4; ++j) {
#pragma unroll
      for (int r = 0; r < 4; ++r) {
        int row = m0 + wr + i * 16 + quad * 4 + r;
        int col = n0 + wc + j * 16 + l15;
        size_t idx = (size_t)row * ldc + col;
        float c = acc[i][j][r];
        if (MODE == 1) {
          float v = beta * velin[idx] + c;
          v = fminf(8.f, fmaxf(-8.f, v));
          velout[idx] = v;
          Cf[idx] = xin[idx] + v;
        } else if (MODE == 2) {
          Cb[idx] = (bf16)c;
        } else {
          Cf[idx] = xin[idx] + c;
        }
      }
    }
  }
}

// ---------------- per-head RMSNorm + RoPE for q,k (v handled separately) -----
// q outputs pre-scaled by 1/sqrt(HD).
__global__ __launch_bounds__(256) void qk_norm_rope(
    const bf16* __restrict__ qkv, const float* __restrict__ qw, const float* __restrict__ kw,
    const float* __restrict__ freqs, bf16* __restrict__ qh, bf16* __restrict__ kh) {
  int row = blockIdx.x;  // b*S + s
  int b = row >> 11, s = row & 2047;
  int tid = threadIdx.x, wvid = tid >> 6, lane = tid & 63;
  float cs = freqs[(size_t)(s * 64 + lane) * 2 + 0];
  float sn = freqs[(size_t)(s * 64 + lane) * 2 + 1];
  for (int slot = wvid; slot < 20; slot += 4) {
    const bf16* base = qkv + (size_t)row * 3072 + slot * 128;
    float t0 = (float)base[2 * lane], t1 = (float)base[2 * lane + 1];
    float ss = t0 * t0 + t1 * t1;
    for (int off = 32; off; off >>= 1) ss += __shfl_xor(ss, off);
    float rstd = rsqrtf(ss * (1.f / 128.f) + 1e-6f);
    const float* w = (slot < 16) ? qw : kw;
    float sc = (slot < 16) ? 0.08838834764831845f : 1.f;  // fold 1/sqrt(128) into q
    float n0 = t0 * rstd * w[2 * lane], n1 = t1 * rstd * w[2 * lane + 1];
    bf16x2 o;
    o[0] = (bf16)((n0 * cs - n1 * sn) * sc);
    o[1] = (bf16)((n0 * sn + n1 * cs) * sc);
    if (slot < 16)
      *(bf16x2*)(qh + ((size_t)(b * Hc + slot) * Sc + s) * HDc + 2 * lane) = o;
    else
      *(bf16x2*)(kh + ((size_t)(b * KVc + (slot - 16)) * Sc + s) * HDc + 2 * lane) = o;
  }
}

// ---------------- strict-causal GQA flash attention --------------------------
// grid (16 pairs, H, B); block 256 = 4 waves; wave owns 16 q-rows.
// Block processes q-tiles p and 31-p (uniform 68 k-tile iterations per block).
__global__ __launch_bounds__(256) void flash_attn(
    const bf16* __restrict__ qh, const bf16* __restrict__ kh, const bf16* __restrict__ vht,
    bf16* __restrict__ attn) {
  __shared__ bf16 Ks[32 * 136];     // [k][d] pitch 136
  __shared__ bf16 Vs[128 * 40];     // [d][k] pitch 40 (staged from pre-transposed vht)
  __shared__ bf16 Ps[4 * 16 * 40];  // per-wave P transpose scratch
  const int tid = threadIdx.x, lane = tid & 63, wvid = tid >> 6;
  const int quad = lane >> 4, l15 = lane & 15;
  const int pairp = blockIdx.x;
  const int h = blockIdx.y, b = blockIdx.z, g = h >> 2;
  const bf16* qbase = qh + (size_t)(b * Hc + h) * Sc * HDc;
  const bf16* kbase = kh + (size_t)(b * KVc + g) * Sc * HDc;
  const bf16* vbase = vht + (size_t)(b * KVc + g) * HDc * Sc;  // [d][s]
  const f32x4 zf = {0.f, 0.f, 0.f, 0.f};
  bf16* pw = Ps + wvid * 16 * 40;

  for (int pass = 0; pass < 2; ++pass) {
    const int qt = pass ? 31 - pairp : pairp;
    const int q0 = qt * 64 + wvid * 16;

    bf16x8 qf[4];
#pragma unroll
    for (int f = 0; f < 4; ++f)
      qf[f] = *(const bf16x8*)(qbase + (size_t)(q0 + l15) * HDc + f * 32 + quad * 8);

    f32x4 Oa[8];
#pragma unroll
    for (int i = 0; i < 8; ++i) Oa[i] = zf;
    float m_i[4], l_i[4];
#pragma unroll
    for (int r = 0; r < 4; ++r) { m_i[r] = -3e38f; l_i[r] = 0.f; }

    const int ntiles = 2 * qt + 2;

    for (int kt = 0; kt < ntiles; ++kt) {
      const int k0 = kt * 32;
      __syncthreads();  // protect Ks/Vs/Ps from previous iteration's readers
      {
        int ch = tid & 15, kk = tid >> 4;       // K: [32k][128d]
#pragma unroll
        for (int it = 0; it < 2; ++it) {
          int kk2 = kk + it * 16;
          *(bf16x8*)(Ks + kk2 * 136 + ch * 8) =
              *(const bf16x8*)(kbase + (size_t)(k0 + kk2) * HDc + ch * 8);
        }
        int dd = tid >> 2, ck = tid & 3;        // V^T: [128d][32k]
#pragma unroll
        for (int it = 0; it < 2; ++it) {
          int d2 = dd + it * 64;
          *(bf16x8*)(Vs + d2 * 40 + ck * 8) =
              *(const bf16x8*)(vbase + (size_t)d2 * Sc + k0 + ck * 8);
        }
      }
      __syncthreads();

      f32x4 sc0 = zf, sc1 = zf;
#pragma unroll
      for (int f = 0; f < 4; ++f) {
        bf16x8 kf = *(const bf16x8*)(Ks + l15 * 136 + f * 32 + quad * 8);
        sc0 = __builtin_amdgcn_mfma_f32_16x16x32_bf16(qf[f], kf, sc0, 0, 0, 0);
      }
#pragma unroll
      for (int f = 0; f < 4; ++f) {
        bf16x8 kf = *(const bf16x8*)(Ks + (16 + l15) * 136 + f * 32 + quad * 8);
        sc1 = __builtin_amdgcn_mfma_f32_16x16x32_bf16(qf[f], kf, sc1, 0, 0, 0);
      }

      float mx[4], al[4], rs[4];
#pragma unroll
      for (int r = 0; r < 4; ++r) {
        int qg = q0 + quad * 4 + r;
        float s0 = (k0 + l15 < qg) ? sc0[r] : -3e38f;       // strict causal k<q
        float s1 = (k0 + 16 + l15 < qg) ? sc1[r] : -3e38f;  // (q pre-scaled)
        sc0[r] = s0; sc1[r] = s1;
        mx[r] = fmaxf(s0, s1);
      }
#pragma unroll
      for (int off = 8; off; off >>= 1)
#pragma unroll
        for (int r = 0; r < 4; ++r) mx[r] = fmaxf(mx[r], __shfl_xor(mx[r], off));
#pragma unroll
      for (int r = 0; r < 4; ++r) {
        float mn = fmaxf(m_i[r], mx[r]);
        al[r] = __expf(m_i[r] - mn);
        m_i[r] = mn;
        float p0 = (sc0[r] > -1e37f) ? __expf(sc0[r] - mn) : 0.f;
        float p1 = (sc1[r] > -1e37f) ? __expf(sc1[r] - mn) : 0.f;
        sc0[r] = p0; sc1[r] = p1;
        rs[r] = p0 + p1;
      }
#pragma unroll
      for (int off = 8; off; off >>= 1)
#pragma unroll
        for (int r = 0; r < 4; ++r) rs[r] += __shfl_xor(rs[r], off);
#pragma unroll
      for (int r = 0; r < 4; ++r) l_i[r] = l_i[r] * al[r] + rs[r];
#pragma unroll
      for (int i = 0; i < 8; ++i)
#pragma unroll
        for (int r = 0; r < 4; ++r) Oa[i][r] *= al[r];

#pragma unroll
      for (int r = 0; r < 4; ++r) {
        pw[(quad * 4 + r) * 40 + l15] = (bf16)sc0[r];
        pw[(quad * 4 + r) * 40 + 16 + l15] = (bf16)sc1[r];
      }
      __syncthreads();
      bf16x8 pf = *(const bf16x8*)(pw + l15 * 40 + quad * 8);
#pragma unroll
      for (int i = 0; i < 8; ++i) {
        bf16x8 vf = *(const bf16x8*)(Vs + (i * 16 + l15) * 40 + quad * 8);
        Oa[i] = __builtin_amdgcn_mfma_f32_16x16x32_bf16(pf, vf, Oa[i], 0, 0, 0);
      }
    }

#pragma unroll
    for (int r = 0; r < 4; ++r) {
      float inv = (l_i[r] > 0.f) ? 1.f / l_i[r] : 0.f;  // q=0 row fully masked -> 0
      int qg = q0 + quad * 4 + r;
      bf16* orow = attn + (size_t)(b * Sc + qg) * Dc + h * HDc;
#pragma unroll
      for (int i = 0; i < 8; ++i) orow[i * 16 + l15] = (bf16)(Oa[i][r] * inv);
    }
  }
}

// ---------------- SwiGLU in-place: g[:, :5632] = silu(g1)*g3 -----------------
__global__ __launch_bounds__(256) void silu_mul_ip(bf16* __restrict__ g) {
  int row = blockIdx.y * 4 + (threadIdx.x >> 6);
  int j0 = (blockIdx.x * 64 + (threadIdx.x & 63)) * 8;
  bf16* p = g + (size_t)row * (2 * FFNc) + j0;
  const bf16x8 a = *(const bf16x8*)p;
  const bf16x8 bb = *(const bf16x8*)(p + FFNc);
  bf16x8 o;
#pragma unroll
  for (int e = 0; e < 8; ++e) {
    float xa = (float)a[e], xb = (float)bb[e];
    float s = xa / (1.f + __expf(-xa));
    o[e] = (bf16)(s * xb);
  }
  *(bf16x8*)p = o;
}

// ---------------- launch ------------------------------------------------------
extern "C" void kernel_launch(void* const* d_in, const int* in_sizes, int n_in,
                              void* d_out, int out_size, void* d_ws, size_t ws_size,
                              hipStream_t stream) {
  (void)in_sizes; (void)n_in; (void)out_size; (void)ws_size;
  const float* x    = (const float*)d_in[0];
  const float* vel  = (const float*)d_in[1];
  const float* frq  = (const float*)d_in[2];
  const float* prew = (const float*)d_in[3];
  const float* wq   = (const float*)d_in[4];
  const float* wk   = (const float*)d_in[5];
  const float* wvw  = (const float*)d_in[6];
  const float* wo   = (const float*)d_in[7];
  const float* qnw  = (const float*)d_in[8];
  const float* knw  = (const float*)d_in[9];
  const float* lb   = (const float*)d_in[10];
  const float* ffnw = (const float*)d_in[11];
  const float* w1   = (const float*)d_in[12];
  const float* w3   = (const float*)d_in[13];
  const float* w2   = (const float*)d_in[14];

  float* out0 = (float*)d_out;                  // final x (also residual scratch)
  float* out1 = out0 + (size_t)Rc * Dc;         // velocity

  // ---- workspace arena: 126 MiB total ----
  char* ws = (char*)d_ws;
  bf16* W  = (bf16*)ws;                                   // 23.07 MB weight region (serial reuse)
  bf16* R1 = (bf16*)(ws + (size_t)23068672);              // 16.78 MB: hbuf -> attn -> normed
  bf16* G  = (bf16*)(ws + (size_t)23068672 + 16777216);   // 92.27 MB: qkv/heads -> gbuf
  bf16* hbuf   = R1;
  bf16* attn   = R1;
  bf16* normed = R1;
  bf16* qkvb   = G;                                       // 4096 x 3072 bf16
  bf16* qhb    = G + (size_t)4096 * 3072;                 // 2*16*2048*128
  bf16* khb    = qhb + (size_t)2 * 16 * 2048 * 128;       // 2*4*2048*128
  bf16* vht    = khb + (size_t)2 * 4 * 2048 * 128;        // V^T [b][g][128][2048]
  bf16* gbuf   = G;                                       // 4096 x 11264 (born after heads die)

  dim3 tb(32, 8);

  // QKV projection
  transpose_cast<<<dim3(64, 64), tb, 0, stream>>>(wq, W, 2048, 2048, 0, 2048);
  transpose_cast<<<dim3(16, 64), tb, 0, stream>>>(wk, W, 2048, 512, 2048, 2048);
  transpose_cast<<<dim3(16, 64), tb, 0, stream>>>(wvw, W, 2048, 512, 2560, 2048);
  rmsnorm_cast<<<Rc, 256, 0, stream>>>(x, prew, hbuf);
  gemm_bt<2><<<dim3(24, 32), 256, 0, stream>>>(hbuf, 2048, W, nullptr, qkvb, nullptr, nullptr,
                                               nullptr, nullptr, 4096, 3072, 2048, 3072);
  qk_norm_rope<<<Rc, 256, 0, stream>>>(qkvb, qnw, knw, frq, qhb, khb);
  transpose_v<<<dim3(64, 4, 8), tb, 0, stream>>>(qkvb, vht);

  // attention + Wo + velocity/residual (writes out0, out1)
  flash_attn<<<dim3(16, Hc, Bc), 256, 0, stream>>>(qhb, khb, vht, attn);
  transpose_cast<<<dim3(64, 64), tb, 0, stream>>>(wo, W, 2048, 2048, 0, 2048);
  gemm_bt<1><<<dim3(16, 32), 256, 0, stream>>>(attn, 2048, W, out0, nullptr, x, vel, lb, out1,
                                               4096, 2048, 2048, 2048);

  // FFN
  rmsnorm_cast<<<Rc, 256, 0, stream>>>(out0, ffnw, normed);
  transpose_cast<<<dim3(176, 64), tb, 0, stream>>>(w1, W, 2048, 5632, 0, 2048);
  gemm_bt<2><<<dim3(44, 32), 256, 0, stream>>>(normed, 2048, W, nullptr, gbuf, nullptr, nullptr,
                                               nullptr, nullptr, 4096, 5632, 2048, 11264);
  transpose_cast<<<dim3(176, 64), tb, 0, stream>>>(w3, W, 2048, 5632, 0, 2048);
  gemm_bt<2><<<dim3(44, 32), 256, 0, stream>>>(normed, 2048, W, nullptr, gbuf + FFNc, nullptr,
                                               nullptr, nullptr, nullptr, 4096, 5632, 2048, 11264);
  silu_mul_ip<<<dim3(11, 1024), 256, 0, stream>>>(gbuf);
  transpose_cast<<<dim3(64, 176), tb, 0, stream>>>(w2, W, 5632, 2048, 0, 5632);
  gemm_bt<3><<<dim3(16, 32), 256, 0, stream>>>(gbuf, 11264, W, out0, nullptr, out0, nullptr,
                                               nullptr, nullptr, 4096, 2048, 5632, 2048);
}